// Round 15
// baseline (93.537 us; speedup 1.0000x reference)
//
#include <hip/hip_runtime.h>
#include <hip/hip_bf16.h>

#define C_DIM 256
#define W_DIM 4096
#define LDS_BYTES 76928
#define XROW 1040            // u16 per kk strip: 130 cols x 8

typedef unsigned short u16;
typedef short s16x8 __attribute__((ext_vector_type(8)));
typedef unsigned short u16x8 __attribute__((ext_vector_type(8)));
typedef unsigned short u16x4 __attribute__((ext_vector_type(4)));
typedef float f32x16 __attribute__((ext_vector_type(16)));

__device__ __forceinline__ u16 f2b(float f) {
  return __builtin_bit_cast(u16, __float2bfloat16(f));
}
__device__ __forceinline__ float b2f(u16 u) {
  return __builtin_bit_cast(float, ((unsigned)u) << 16);
}

// ---------------- prep kernel (unchanged) ----------------
// ws: [0,131072) M bf16 [256][256]; [131072,262144) Wv bf16;
//     [262144) u0[256] f32; [263168) u1[256] f32; [264192) c0 f32
__global__ __launch_bounds__(256) void prep_kernel(
    const float* __restrict__ Wq, const float* __restrict__ bq,
    const float* __restrict__ Wk, const float* __restrict__ bk,
    const float* __restrict__ Wv, char* __restrict__ ws) {
  u16* Mb   = (u16*)ws;
  u16* Wvb  = (u16*)(ws + 131072);
  float* u0 = (float*)(ws + 262144);
  float* u1 = (float*)(ws + 263168);
  float* c0p = (float*)(ws + 264192);
  int bid = blockIdx.x, t = threadIdx.x;
  if (bid < 256) {
    __shared__ float Wqs[256*17];
    __shared__ float Wks[256*17];
    int i0 = (bid >> 4) << 4, j0 = (bid & 15) << 4;
    for (int it = 0; it < 16; ++it) {
      int e = t + 256*it; int a = e >> 4, ii = e & 15;
      Wqs[a*17+ii] = Wq[a*256 + i0 + ii];
      Wks[a*17+ii] = Wk[a*256 + j0 + ii];
    }
    __syncthreads();
    int ii = t >> 4, jj = t & 15;
    float acc = 0.f;
    #pragma unroll 8
    for (int a = 0; a < 256; ++a) acc += Wqs[a*17+ii] * Wks[a*17+jj];
    Mb[(i0+ii)*256 + j0 + jj] = f2b(acc);
  } else if (bid == 256) {
    int j = t;
    float a0 = 0.f, a1 = 0.f;
    #pragma unroll 4
    for (int a = 0; a < 256; ++a) {
      a0 += bq[a] * Wk[a*256 + j];
      a1 += bk[a] * Wq[a*256 + j];
    }
    u0[j] = a0; u1[j] = a1;
    __shared__ float red[256];
    red[t] = bq[t] * bk[t];
    __syncthreads();
    if (t == 0) { float s = 0.f; for (int a = 0; a < 256; ++a) s += red[a]; *c0p = s; }
  } else {
    int base = ((bid - 257)*256 + t) * 4;
    const float4 v = *reinterpret_cast<const float4*>(Wv + base);
    ushort4 pk = make_ushort4(f2b(v.x), f2b(v.y), f2b(v.z), f2b(v.w));
    *reinterpret_cast<ushort4*>(Wvb + base) = pk;
  }
}

// ---------------- main fused kernel ----------------
// 512 blocks = (b 0..15) x (tile 0..31 of 128 out cols). 512 thr (8 waves).
// Targets: <=128 regs/wave (acc[4]=64 AGPR) -> 4 waves/SIMD; LDS 76928 -> 2 blk/CU.
// Phase-staggered co-resident blocks overlap P0/stores with compute.
// wave wv: rows 32wv (GEMM row tile), strips kk=4wv..4wv+3, all 4 n-tiles.
// Tail G-cols 128/129 via f-pass (f1,f2,f3 quadratic forms).
// LDS:
//   Xt  [kk 0..31][j 0..129][e 0..7] bf16  66560 @0
//   Ps  [3][4][130] f32 (atomicAdd, PsA planes 0/1 overlay)  6240 @66560
//   ABs [2][130] f32                        1040 @72800
//   fS  [4] f32                               16 @73840
//   U   [2][256] f32                        2048 @73856
//   bvs [256] f32                           1024 @75904
__global__ __launch_bounds__(512, 4) void main_kernel(
    const float* __restrict__ x, const char* __restrict__ ws,
    const float* __restrict__ bv, float* __restrict__ out) {
  const u16* Mb   = (const u16*)ws;
  const u16* Wvb  = (const u16*)(ws + 131072);
  const float* u0g = (const float*)(ws + 262144);
  const float* u1g = (const float*)(ws + 263168);
  const float c0  = *(const float*)(ws + 264192);

  extern __shared__ char lds[];
  u16*   Xt  = (u16*)lds;
  float* Ps  = (float*)(lds + 66560);
  float* ABs = (float*)(lds + 72800);
  float* fS  = (float*)(lds + 73840);
  float* U   = (float*)(lds + 73856);
  float* bvs = (float*)(lds + 75904);

  const int bid = blockIdx.x;
  const int t = threadIdx.x;
  const int wv = t >> 6, l = t & 63;
  const int col = l & 31, half = l >> 5;
  const int g4 = wv & 3;
  const int kkA = 4*wv;

  const int b  = bid >> 5;
  const int cw = bid & 31;
  const int w0 = cw << 7;
  const float* xb = x + (size_t)b * (C_DIM*W_DIM);
  float* outb = out + (size_t)b * (C_DIM*W_DIM);

  // ---- prologue: zero Ps/fS, stage U/bvs ----
  for (int i = t; i < 1560; i += 512) Ps[i] = 0.f;
  if (t < 4) fS[t] = 0.f;
  if (t < 256) { U[t] = u0g[t]; U[256+t] = u1g[t]; bvs[t] = bv[t]; }
  __syncthreads();

  // ---- P0: stage x -> Xt bf16 (strips kkA..kkA+3) + alpha/beta partials ----
  {
    #pragma unroll
    for (int p = 0; p < 2; ++p) {
      int j = 64*p + l;
      int w = w0 - 1 + j;                  // <= 4094, only lower bound can fail
      bool ok = (w >= 0);
      const float* xp = xb + w;
      float pa = 0.f, pb_ = 0.f;
      #pragma unroll
      for (int h = 0; h < 2; ++h) {
        float xr[16];
        #pragma unroll
        for (int g2 = 0; g2 < 2; ++g2)
          #pragma unroll
          for (int e = 0; e < 8; ++e)
            xr[g2*8+e] = ok ? xp[(size_t)((kkA+2*h+g2)*8 + e) * W_DIM] : 0.f;
        #pragma unroll
        for (int g2 = 0; g2 < 2; ++g2) {
          int kk = kkA + 2*h + g2;
          union { u16 u[8]; u16x8 v; } pk;
          #pragma unroll
          for (int e = 0; e < 8; ++e) {
            float v = xr[g2*8+e];
            pk.u[e] = f2b(v);
            pa  += U[kk*8+e] * v;
            pb_ += U[256 + kk*8+e] * v;
          }
          *reinterpret_cast<u16x8*>(Xt + kk*XROW + j*8) = pk.v;
        }
      }
      atomicAdd(&Ps[g4*130 + j], pa);
      atomicAdd(&Ps[520 + g4*130 + j], pb_);
    }
    if (l < 2) {                           // j = 128,129
      int j = 128 + l;
      int w = w0 - 1 + j;
      bool real = (w < W_DIM);
      const float* xpe = xb + w;
      float pa = 0.f, pb_ = 0.f;
      #pragma unroll
      for (int g = 0; g < 4; ++g) {
        int kk = kkA + g;
        union { u16 u[8]; u16x8 v; } pk;
        #pragma unroll
        for (int e = 0; e < 8; ++e) {
          float v = real ? xpe[(size_t)(kk*8+e) * W_DIM] : 0.f;
          pk.u[e] = f2b(v);
          pa  += U[kk*8+e] * v;
          pb_ += U[256 + kk*8+e] * v;
        }
        *reinterpret_cast<u16x8*>(Xt + kk*XROW + j*8) = pk.v;
      }
      atomicAdd(&Ps[g4*130 + j], pa);
      atomicAdd(&Ps[520 + g4*130 + j], pb_);
    }
  }
  __syncthreads();   // bar1: Xt + PsA complete

  // ---- GEMM1: G = M @ X; wave = rows 32wv x 4 n-tiles ----
  f32x16 acc[4];
  #pragma unroll
  for (int ni = 0; ni < 4; ++ni)
    #pragma unroll
    for (int r = 0; r < 16; ++r) acc[ni][r] = 0.f;
  {
    const u16* Arow = Mb + (32*wv + col)*256 + 8*half;
    #pragma unroll
    for (int kk = 0; kk < 16; ++kk) {
      s16x8 a = *reinterpret_cast<const s16x8*>(Arow + 16*kk);
      const u16* Bb = Xt + (2*kk + half)*XROW;
      #pragma unroll
      for (int ni = 0; ni < 4; ++ni) {
        s16x8 bfr = *reinterpret_cast<const s16x8*>(Bb + (32*ni + col)*8);
        acc[ni] = __builtin_amdgcn_mfma_f32_32x32x16_bf16(a, bfr, acc[ni], 0, 0, 0);
      }
    }
  }

  // ---- f-pass: f1=x128'Mx128, f2=x128'Mx129, f3=x127'Mx128 ----
  {
    int i = t >> 1, kq = t & 1;            // i = M row, kq = k-half
    float xi127 = b2f(Xt[(i>>3)*XROW + 127*8 + (i&7)]);
    float xi128 = b2f(Xt[(i>>3)*XROW + 128*8 + (i&7)]);
    float a1 = 0.f, a2 = 0.f;
    const u16* Mrow = Mb + i*256 + 128*kq;
    #pragma unroll
    for (int kk8 = 0; kk8 < 16; ++kk8) {
      int sA = 16*kq + kk8;
      s16x8 m8 = *reinterpret_cast<const s16x8*>(Mrow + 8*kk8);
      u16x8 xk6 = *reinterpret_cast<const u16x8*>(Xt + sA*XROW + 128*8);
      u16x8 xk7 = *reinterpret_cast<const u16x8*>(Xt + sA*XROW + 129*8);
      #pragma unroll
      for (int e = 0; e < 8; ++e) {
        float m = b2f((u16)m8[e]);
        a1 += m * b2f(xk6[e]);
        a2 += m * b2f(xk7[e]);
      }
    }
    float p1 = xi128*a1, p2 = xi128*a2, p3 = xi127*a1;
    #pragma unroll
    for (int d = 1; d < 64; d <<= 1) {
      p1 += __shfl_xor(p1, d); p2 += __shfl_xor(p2, d); p3 += __shfl_xor(p3, d);
    }
    if (l == 0) { atomicAdd(&fS[0], p1); atomicAdd(&fS[1], p2); atomicAdd(&fS[2], p3); }
  }
  // alpha/beta reduce, then re-zero own column (each jj touched by one thread)
  if (t < 260) {
    int which = (t >= 130) ? 1 : 0;
    int jj = t - 130*which;
    float s = 0.f;
    #pragma unroll
    for (int g = 0; g < 4; ++g) s += Ps[which*520 + g*130 + jj];
    ABs[which*130 + jj] = s;
  }
  __syncthreads();
  if (t < 130) {
    #pragma unroll
    for (int pl = 0; pl < 3; ++pl)
      #pragma unroll
      for (int g = 0; g < 4; ++g) Ps[pl*520 + g*130 + t] = 0.f;
  }
  __syncthreads();   // bar2: PsB zeroed, ABs/fS ready

  // ---- P2: score partials from acc -> PsB (atomicAdd, 2 waves per group) ----
  {
    #pragma unroll
    for (int ni = 0; ni < 4; ++ni) {
      int jt = 32*ni + col;                // 0..127
      int jm = (jt > 0) ? jt-1 : 0;
      int jp = jt + 1;                     // <= 128
      float s0 = 0.f, s1 = 0.f, s2 = 0.f;
      #pragma unroll
      for (int q = 0; q < 4; ++q) {
        const u16* base = Xt + (kkA + q)*XROW + 4*half*1;   // strips of own rows
        u16x4 xm = *reinterpret_cast<const u16x4*>(base + jm*8);
        u16x4 xc = *reinterpret_cast<const u16x4*>(base + jt*8);
        u16x4 xp = *reinterpret_cast<const u16x4*>(base + jp*8);
        #pragma unroll
        for (int r4 = 0; r4 < 4; ++r4) {
          float g0 = acc[ni][4*q + r4];
          s2 += g0 * b2f(xm[r4]);
          s1 += g0 * b2f(xc[r4]);
          s0 += g0 * b2f(xp[r4]);
        }
      }
      s0 += __shfl_xor(s0, 32);
      s1 += __shfl_xor(s1, 32);
      s2 += __shfl_xor(s2, 32);
      if (half == 0) {
        atomicAdd(&Ps[0*520 + g4*130 + jt+1], s0);
        if (jt >= 1) atomicAdd(&Ps[1*520 + g4*130 + jt], s1);
        if (jt >= 2) atomicAdd(&Ps[2*520 + g4*130 + jt-1], s2);
      }
    }
  }
  __syncthreads();   // bar3

  // ---- softmax (oc = 64p+l) + in-place mix of own 4 strips ----
  {
    float aw0[2], aw1[2], aw2[2];
    #pragma unroll
    for (int p = 0; p < 2; ++p) {
      int oc = 64*p + l;
      int jp = oc + 1;                     // 1..128
      float d0 = 0.f, d1 = 0.f, d2 = 0.f;
      #pragma unroll
      for (int g = 0; g < 4; ++g) {
        d0 += Ps[0*520 + g*130 + jp];
        d1 += Ps[1*520 + g*130 + jp];
        d2 += Ps[2*520 + g*130 + jp];
      }
      if (oc == 127)      { d1 = fS[0]; d2 = fS[1]; }
      else if (oc == 126) { d2 = fS[2]; }
      float am = ABs[jp-1], ac_ = ABs[jp], ap_ = ABs[jp+1];
      float be = ABs[130 + jp];
      float sc0 = (d0 + am + be + c0) * 0.0625f;
      float sc1 = (d1 + ac_ + be + c0) * 0.0625f;
      float sc2 = (d2 + ap_ + be + c0) * 0.0625f;
      int w = w0 + oc;
      bool v0 = (w >= 1), v2 = (w + 1 < W_DIM);
      const float NEG = -1e30f;
      float m = fmaxf(v0 ? sc0 : NEG, fmaxf(sc1, v2 ? sc2 : NEG));
      float e0v = v0 ? __expf(sc0 - m) : 0.f;
      float e1v = __expf(sc1 - m);
      float e2v = v2 ? __expf(sc2 - m) : 0.f;
      float inv = 1.f / (e0v + e1v + e2v);
      aw0[p] = e0v*inv; aw1[p] = e1v*inv; aw2[p] = e2v*inv;
    }
    #pragma unroll
    for (int g = 0; g < 4; ++g) {
      u16* base = Xt + (kkA + g)*XROW;
      u16x8 xrd[6];
      #pragma unroll
      for (int p = 0; p < 2; ++p)
        #pragma unroll
        for (int i = 0; i < 3; ++i)
          xrd[p*3+i] = *reinterpret_cast<const u16x8*>(base + (64*p + l + i)*8);
      __builtin_amdgcn_sched_barrier(0);
      #pragma unroll
      for (int p = 0; p < 2; ++p) {
        union { u16 u[8]; u16x8 v; } pk;
        #pragma unroll
        for (int e = 0; e < 8; ++e)
          pk.u[e] = f2b(aw0[p]*b2f(xrd[p*3][e]) + aw1[p]*b2f(xrd[p*3+1][e])
                        + aw2[p]*b2f(xrd[p*3+2][e]));
        *reinterpret_cast<u16x8*>(base + (64*p + l + 1)*8) = pk.v;
      }
      __builtin_amdgcn_sched_barrier(0);
    }
  }
  __syncthreads();   // bar4

  // ---- GEMM2: out = Wv @ Xmix + bv; dense aligned stores ----
  {
    #pragma unroll
    for (int ni = 0; ni < 4; ++ni)
      #pragma unroll
      for (int r = 0; r < 16; ++r) acc[ni][r] = 0.f;
    const u16* Arow2 = Wvb + (32*wv + col)*256 + 8*half;
    #pragma unroll
    for (int kk = 0; kk < 16; ++kk) {
      s16x8 a = *reinterpret_cast<const s16x8*>(Arow2 + 16*kk);
      const u16* Bb = Xt + (2*kk + half)*XROW;
      #pragma unroll
      for (int ni = 0; ni < 4; ++ni) {
        s16x8 bfr = *reinterpret_cast<const s16x8*>(Bb + (1 + 32*ni + col)*8);
        acc[ni] = __builtin_amdgcn_mfma_f32_32x32x16_bf16(a, bfr, acc[ni], 0, 0, 0);
      }
    }
    #pragma unroll
    for (int ni = 0; ni < 4; ++ni)
      #pragma unroll
      for (int r = 0; r < 16; ++r) {
        int crow = 32*wv + (r&3) + 8*(r>>2) + 4*half;
        outb[(size_t)crow*W_DIM + w0 + 32*ni + col] = acc[ni][r] + bvs[crow];
      }
  }
}

extern "C" void kernel_launch(void* const* d_in, const int* in_sizes, int n_in,
                              void* d_out, int out_size, void* d_ws, size_t ws_size,
                              hipStream_t stream) {
  (void)in_sizes; (void)n_in; (void)out_size; (void)ws_size;
  const float* x  = (const float*)d_in[0];
  const float* Wq = (const float*)d_in[1];
  const float* bq = (const float*)d_in[2];
  const float* Wk = (const float*)d_in[3];
  const float* bk = (const float*)d_in[4];
  const float* Wv = (const float*)d_in[5];
  const float* bv = (const float*)d_in[6];
  float* out = (float*)d_out;
  char* ws = (char*)d_ws;   // needs 264196 B

  hipFuncSetAttribute((const void*)main_kernel,
                      hipFuncAttributeMaxDynamicSharedMemorySize, LDS_BYTES);
  prep_kernel<<<321, 256, 0, stream>>>(Wq, bq, Wk, bk, Wv, ws);
  main_kernel<<<512, 512, LDS_BYTES, stream>>>(x, ws, bv, out);
}

// Round 16
// 85.266 us; speedup vs baseline: 1.0970x; 1.0970x over previous
//
#include <hip/hip_runtime.h>
#include <hip/hip_bf16.h>

#define C_DIM 256
#define W_DIM 4096
#define LDS_BYTES 162528

typedef unsigned short u16;
typedef short s16x8 __attribute__((ext_vector_type(8)));
typedef unsigned short u16x8 __attribute__((ext_vector_type(8)));
typedef unsigned short u16x4 __attribute__((ext_vector_type(4)));
typedef float f32x16 __attribute__((ext_vector_type(16)));

__device__ __forceinline__ u16 f2b(float f) {
  return __builtin_bit_cast(u16, __float2bfloat16(f));
}
__device__ __forceinline__ float b2f(u16 u) {
  return __builtin_bit_cast(float, ((unsigned)u) << 16);
}

// ---------------- prep kernel (unchanged) ----------------
// ws: [0,131072) M bf16 [256][256]; [131072,262144) Wv bf16;
//     [262144) u0[256] f32; [263168) u1[256] f32; [264192) c0 f32
__global__ __launch_bounds__(256) void prep_kernel(
    const float* __restrict__ Wq, const float* __restrict__ bq,
    const float* __restrict__ Wk, const float* __restrict__ bk,
    const float* __restrict__ Wv, char* __restrict__ ws) {
  u16* Mb   = (u16*)ws;
  u16* Wvb  = (u16*)(ws + 131072);
  float* u0 = (float*)(ws + 262144);
  float* u1 = (float*)(ws + 263168);
  float* c0p = (float*)(ws + 264192);
  int bid = blockIdx.x, t = threadIdx.x;
  if (bid < 256) {
    __shared__ float Wqs[256*17];
    __shared__ float Wks[256*17];
    int i0 = (bid >> 4) << 4, j0 = (bid & 15) << 4;
    for (int it = 0; it < 16; ++it) {
      int e = t + 256*it; int a = e >> 4, ii = e & 15;
      Wqs[a*17+ii] = Wq[a*256 + i0 + ii];
      Wks[a*17+ii] = Wk[a*256 + j0 + ii];
    }
    __syncthreads();
    int ii = t >> 4, jj = t & 15;
    float acc = 0.f;
    #pragma unroll 8
    for (int a = 0; a < 256; ++a) acc += Wqs[a*17+ii] * Wks[a*17+jj];
    Mb[(i0+ii)*256 + j0 + jj] = f2b(acc);
  } else if (bid == 256) {
    int j = t;
    float a0 = 0.f, a1 = 0.f;
    #pragma unroll 4
    for (int a = 0; a < 256; ++a) {
      a0 += bq[a] * Wk[a*256 + j];
      a1 += bk[a] * Wq[a*256 + j];
    }
    u0[j] = a0; u1[j] = a1;
    __shared__ float red[256];
    red[t] = bq[t] * bk[t];
    __syncthreads();
    if (t == 0) { float s = 0.f; for (int a = 0; a < 256; ++a) s += red[a]; *c0p = s; }
  } else {
    int base = ((bid - 257)*256 + t) * 4;
    const float4 v = *reinterpret_cast<const float4*>(Wv + base);
    ushort4 pk = make_ushort4(f2b(v.x), f2b(v.y), f2b(v.z), f2b(v.w));
    *reinterpret_cast<ushort4*>(Wvb + base) = pk;
  }
}

// ---------------- main fused kernel ----------------
// 256 blocks = (b 0..15) x (tile 0..15 of 256 out cols). 512 thr (8 waves), 1 blk/CU.
// R12 decomposition (wave = 32 rows x all n-tiles) but DE-SPILLED:
//  - acc[4] reused across two 4-n-tile passes per GEMM (64 AGPR not 144)
//  - tail G-cols 256/257 via f-pass (f1,f2,f3) instead of a 9th acc tile
//  - GEMM2 pass-A stores issued before pass-B compute (store/MFMA overlap)
// LDS 162528 B:
//   Xt  [kk 0..31][j 0..258][e 0..7] bf16  132608 @0
//   Ps  [3][8][258] f32 (PsA a/b overlay planes 0/1)  24768 @132608
//   ABs [2][258] f32                         2064 @157376
//   fS  [4] f32                                16 @159440
//   U   [2][256] f32                         2048 @159456
//   bvs [256] f32                            1024 @161504
__global__ __launch_bounds__(512, 2) void main_kernel(
    const float* __restrict__ x, const char* __restrict__ ws,
    const float* __restrict__ bv, float* __restrict__ out) {
  const u16* Mb   = (const u16*)ws;
  const u16* Wvb  = (const u16*)(ws + 131072);
  const float* u0g = (const float*)(ws + 262144);
  const float* u1g = (const float*)(ws + 263168);
  const float c0  = *(const float*)(ws + 264192);

  extern __shared__ char lds[];
  u16*   Xt  = (u16*)lds;
  float* Ps  = (float*)(lds + 132608);
  float* ABs = (float*)(lds + 157376);
  float* fS  = (float*)(lds + 159440);
  float* U   = (float*)(lds + 159456);
  float* bvs = (float*)(lds + 161504);

  const int bid = blockIdx.x;
  const int t = threadIdx.x;
  const int wv = t >> 6, l = t & 63;
  const int col = l & 31, half = l >> 5;

  const int b  = bid >> 4;
  const int cw = bid & 15;
  const int w0 = cw << 8;
  const float* xb = x + (size_t)b * (C_DIM*W_DIM);
  float* outb = out + (size_t)b * (C_DIM*W_DIM);

  if (t < 4) fS[t] = 0.f;
  if (t < 256) { U[t] = u0g[t]; U[256+t] = u1g[t]; bvs[t] = bv[t]; }
  __syncthreads();

  // ---- P0: stage x -> Xt bf16 (wave-private strips 4wv..4wv+3) + a/b partials ----
  {
    #pragma unroll
    for (int p = 0; p < 4; ++p) {
      int j = 64*p + l;
      int w = w0 - 1 + j;                 // w <= 4094, only lower bound can fail
      bool ok = (w >= 0);
      const float* xp = xb + w;
      float xr[32];
      #pragma unroll
      for (int g = 0; g < 4; ++g)
        #pragma unroll
        for (int e = 0; e < 8; ++e)
          xr[g*8+e] = ok ? xp[(size_t)((4*wv+g)*8 + e) * W_DIM] : 0.f;
      float pa = 0.f, pb_ = 0.f;
      #pragma unroll
      for (int g = 0; g < 4; ++g) {
        int kk = 4*wv + g;
        union { u16 u[8]; u16x8 v; } pk;
        #pragma unroll
        for (int e = 0; e < 8; ++e) {
          float v = xr[g*8+e];
          pk.u[e] = f2b(v);
          pa  += U[kk*8+e] * v;
          pb_ += U[256 + kk*8+e] * v;
        }
        *reinterpret_cast<u16x8*>(Xt + (kk*259 + j)*8) = pk.v;
      }
      Ps[wv*258 + j] = pa;
      Ps[2064 + wv*258 + j] = pb_;
    }
    if (l < 3) {                           // j = 256,257 real; 258 zero pad
      int j = 256 + l;
      int w = w0 - 1 + j;
      bool real = (l < 2) && (w < W_DIM);
      const float* xpe = xb + w;
      float pa = 0.f, pb_ = 0.f;
      #pragma unroll
      for (int g = 0; g < 4; ++g) {
        int kk = 4*wv + g;
        union { u16 u[8]; u16x8 v; } pk;
        #pragma unroll
        for (int e = 0; e < 8; ++e) {
          float v = real ? xpe[(size_t)(kk*8+e) * W_DIM] : 0.f;
          pk.u[e] = f2b(v);
          pa  += U[kk*8+e] * v;
          pb_ += U[256 + kk*8+e] * v;
        }
        *reinterpret_cast<u16x8*>(Xt + (kk*259 + j)*8) = pk.v;
      }
      if (l < 2) {
        Ps[wv*258 + j] = pa;
        Ps[2064 + wv*258 + j] = pb_;
      }
    }
  }
  __syncthreads();   // bar1

  // ---- GEMM1 pass A: G n-tiles 0..3 (rows 32wv) ----
  f32x16 acc[4];
  #pragma unroll
  for (int ni = 0; ni < 4; ++ni)
    #pragma unroll
    for (int r = 0; r < 16; ++r) acc[ni][r] = 0.f;
  const u16* Arow1 = Mb + (32*wv + col)*256 + 8*half;
  {
    #pragma unroll
    for (int kk = 0; kk < 16; ++kk) {
      s16x8 a = *reinterpret_cast<const s16x8*>(Arow1 + 16*kk);
      const u16* Bb = Xt + (2*kk + half)*259*8;
      #pragma unroll
      for (int ni = 0; ni < 4; ++ni) {
        s16x8 bfr = *reinterpret_cast<const s16x8*>(Bb + (32*ni + col)*8);
        acc[ni] = __builtin_amdgcn_mfma_f32_32x32x16_bf16(a, bfr, acc[ni], 0, 0, 0);
      }
    }
  }

  // ---- f-pass: f1=x256'Mx256, f2=x256'Mx257, f3=x255'Mx256 (tail scores) ----
  {
    int i = t >> 1, kq = t & 1;
    float xi255 = b2f(Xt[((i>>3)*259 + 255)*8 + (i&7)]);
    float xi256 = b2f(Xt[((i>>3)*259 + 256)*8 + (i&7)]);
    float a1 = 0.f, a2 = 0.f;
    const u16* Mrow = Mb + i*256 + 128*kq;
    #pragma unroll
    for (int kk8 = 0; kk8 < 16; ++kk8) {
      int sA = 16*kq + kk8;
      s16x8 m8 = *reinterpret_cast<const s16x8*>(Mrow + 8*kk8);
      u16x8 xk6 = *reinterpret_cast<const u16x8*>(Xt + (sA*259 + 256)*8);
      u16x8 xk7 = *reinterpret_cast<const u16x8*>(Xt + (sA*259 + 257)*8);
      #pragma unroll
      for (int e = 0; e < 8; ++e) {
        float m = b2f((u16)m8[e]);
        a1 += m * b2f(xk6[e]);
        a2 += m * b2f(xk7[e]);
      }
    }
    float p1 = xi256*a1, p2 = xi256*a2, p3 = xi255*a1;
    #pragma unroll
    for (int d = 1; d < 64; d <<= 1) {
      p1 += __shfl_xor(p1, d); p2 += __shfl_xor(p2, d); p3 += __shfl_xor(p3, d);
    }
    if (l == 0) { atomicAdd(&fS[0], p1); atomicAdd(&fS[1], p2); atomicAdd(&fS[2], p3); }
  }
  // alpha/beta reduce (PsA complete since bar1)
  for (int i = t; i < 516; i += 512) {
    int which = (i >= 258) ? 1 : 0;
    int jj = i - 258*which;
    float s = 0.f;
    #pragma unroll
    for (int g = 0; g < 8; ++g) s += Ps[which*2064 + g*258 + jj];
    ABs[which*258 + jj] = s;
  }
  __syncthreads();   // bar2: Ps transitions PsA -> PsB

  // ---- P2 pass A: score partials from acc (n 0..3) -> PsB ----
  {
    #pragma unroll
    for (int ni = 0; ni < 4; ++ni) {
      int jt = 32*ni + col;                // 0..127
      int jm = (jt > 0) ? jt-1 : 0;
      int jp = jt + 1;
      float s0 = 0.f, s1 = 0.f, s2 = 0.f;
      #pragma unroll
      for (int q = 0; q < 4; ++q) {
        const u16* base = Xt + (4*wv + q)*259*8 + 4*half;
        u16x4 xm = *reinterpret_cast<const u16x4*>(base + jm*8);
        u16x4 xc = *reinterpret_cast<const u16x4*>(base + jt*8);
        u16x4 xp = *reinterpret_cast<const u16x4*>(base + jp*8);
        #pragma unroll
        for (int r4 = 0; r4 < 4; ++r4) {
          float g0 = acc[ni][4*q + r4];
          s2 += g0 * b2f(xm[r4]);
          s1 += g0 * b2f(xc[r4]);
          s0 += g0 * b2f(xp[r4]);
        }
      }
      s0 += __shfl_xor(s0, 32);
      s1 += __shfl_xor(s1, 32);
      s2 += __shfl_xor(s2, 32);
      if (half == 0) {
        Ps[0*2064 + wv*258 + jt+1] = s0;
        if (jt >= 1) Ps[1*2064 + wv*258 + jt]   = s1;
        if (jt >= 2) Ps[2*2064 + wv*258 + jt-1] = s2;
      }
    }
  }

  // ---- GEMM1 pass B: G n-tiles 4..7 (acc reused) ----
  #pragma unroll
  for (int ni = 0; ni < 4; ++ni)
    #pragma unroll
    for (int r = 0; r < 16; ++r) acc[ni][r] = 0.f;
  {
    #pragma unroll
    for (int kk = 0; kk < 16; ++kk) {
      s16x8 a = *reinterpret_cast<const s16x8*>(Arow1 + 16*kk);
      const u16* Bb = Xt + (2*kk + half)*259*8;
      #pragma unroll
      for (int ni = 0; ni < 4; ++ni) {
        s16x8 bfr = *reinterpret_cast<const s16x8*>(Bb + (32*(ni+4) + col)*8);
        acc[ni] = __builtin_amdgcn_mfma_f32_32x32x16_bf16(a, bfr, acc[ni], 0, 0, 0);
      }
    }
  }
  // ---- P2 pass B: score partials (n 4..7) -> PsB ----
  {
    #pragma unroll
    for (int ni = 0; ni < 4; ++ni) {
      int jt = 32*(ni+4) + col;            // 128..255 (all guards pass)
      int jm = jt-1;
      int jp = jt + 1;
      float s0 = 0.f, s1 = 0.f, s2 = 0.f;
      #pragma unroll
      for (int q = 0; q < 4; ++q) {
        const u16* base = Xt + (4*wv + q)*259*8 + 4*half;
        u16x4 xm = *reinterpret_cast<const u16x4*>(base + jm*8);
        u16x4 xc = *reinterpret_cast<const u16x4*>(base + jt*8);
        u16x4 xp = *reinterpret_cast<const u16x4*>(base + jp*8);
        #pragma unroll
        for (int r4 = 0; r4 < 4; ++r4) {
          float g0 = acc[ni][4*q + r4];
          s2 += g0 * b2f(xm[r4]);
          s1 += g0 * b2f(xc[r4]);
          s0 += g0 * b2f(xp[r4]);
        }
      }
      s0 += __shfl_xor(s0, 32);
      s1 += __shfl_xor(s1, 32);
      s2 += __shfl_xor(s2, 32);
      if (half == 0) {
        Ps[0*2064 + wv*258 + jt+1] = s0;
        Ps[1*2064 + wv*258 + jt]   = s1;
        Ps[2*2064 + wv*258 + jt-1] = s2;
      }
    }
  }
  __syncthreads();   // bar3

  // ---- softmax (oc = 64p+l) + in-place mix of own 4 strips ----
  {
    float aw0[4], aw1[4], aw2[4];
    #pragma unroll
    for (int p = 0; p < 4; ++p) {
      int oc = 64*p + l;
      int jp = oc + 1;
      float d0 = 0.f, d1 = 0.f, d2 = 0.f;
      #pragma unroll
      for (int g = 0; g < 8; ++g) {
        d0 += Ps[0*2064 + g*258 + jp];
        d1 += Ps[1*2064 + g*258 + jp];
        d2 += Ps[2*2064 + g*258 + jp];
      }
      if (oc == 255)      { d1 = fS[0]; d2 = fS[1]; }
      else if (oc == 254) { d2 = fS[2]; }
      float am = ABs[jp-1], ac_ = ABs[jp], ap_ = ABs[jp+1];
      float be = ABs[258 + jp];
      float sc0 = (d0 + am + be + c0) * 0.0625f;
      float sc1 = (d1 + ac_ + be + c0) * 0.0625f;
      float sc2 = (d2 + ap_ + be + c0) * 0.0625f;
      int w = w0 + oc;
      bool v0 = (w >= 1), v2 = (w + 1 < W_DIM);
      const float NEG = -1e30f;
      float m = fmaxf(v0 ? sc0 : NEG, fmaxf(sc1, v2 ? sc2 : NEG));
      float e0v = v0 ? __expf(sc0 - m) : 0.f;
      float e1v = __expf(sc1 - m);
      float e2v = v2 ? __expf(sc2 - m) : 0.f;
      float inv = 1.f / (e0v + e1v + e2v);
      aw0[p] = e0v*inv; aw1[p] = e1v*inv; aw2[p] = e2v*inv;
    }
    #pragma unroll
    for (int g = 0; g < 4; ++g) {
      u16* base = Xt + (4*wv + g)*259*8;
      u16x8 xrd[12];
      #pragma unroll
      for (int p = 0; p < 4; ++p)
        #pragma unroll
        for (int i = 0; i < 3; ++i)
          xrd[p*3+i] = *reinterpret_cast<const u16x8*>(base + (64*p + l + i)*8);
      __builtin_amdgcn_sched_barrier(0);
      #pragma unroll
      for (int p = 0; p < 4; ++p) {
        union { u16 u[8]; u16x8 v; } pk;
        #pragma unroll
        for (int e = 0; e < 8; ++e)
          pk.u[e] = f2b(aw0[p]*b2f(xrd[p*3][e]) + aw1[p]*b2f(xrd[p*3+1][e])
                        + aw2[p]*b2f(xrd[p*3+2][e]));
        *reinterpret_cast<u16x8*>(base + (64*p + l + 1)*8) = pk.v;
      }
      __builtin_amdgcn_sched_barrier(0);
    }
  }
  __syncthreads();   // bar4

  // ---- GEMM2 pass A: out n-tiles 0..3, stores issued before pass B ----
  const u16* Arow2 = Wvb + (32*wv + col)*256 + 8*half;
  #pragma unroll
  for (int ni = 0; ni < 4; ++ni)
    #pragma unroll
    for (int r = 0; r < 16; ++r) acc[ni][r] = 0.f;
  {
    #pragma unroll
    for (int kk = 0; kk < 16; ++kk) {
      s16x8 a = *reinterpret_cast<const s16x8*>(Arow2 + 16*kk);
      const u16* Bb = Xt + (2*kk + half)*259*8;
      #pragma unroll
      for (int ni = 0; ni < 4; ++ni) {
        s16x8 bfr = *reinterpret_cast<const s16x8*>(Bb + (1 + 32*ni + col)*8);
        acc[ni] = __builtin_amdgcn_mfma_f32_32x32x16_bf16(a, bfr, acc[ni], 0, 0, 0);
      }
    }
    #pragma unroll
    for (int ni = 0; ni < 4; ++ni)
      #pragma unroll
      for (int r = 0; r < 16; ++r) {
        int crow = 32*wv + (r&3) + 8*(r>>2) + 4*half;
        outb[(size_t)crow*W_DIM + w0 + 32*ni + col] = acc[ni][r] + bvs[crow];
      }
  }
  // ---- GEMM2 pass B: out n-tiles 4..7 (stores of pass A still in flight) ----
  #pragma unroll
  for (int ni = 0; ni < 4; ++ni)
    #pragma unroll
    for (int r = 0; r < 16; ++r) acc[ni][r] = 0.f;
  {
    #pragma unroll
    for (int kk = 0; kk < 16; ++kk) {
      s16x8 a = *reinterpret_cast<const s16x8*>(Arow2 + 16*kk);
      const u16* Bb = Xt + (2*kk + half)*259*8;
      #pragma unroll
      for (int ni = 0; ni < 4; ++ni) {
        s16x8 bfr = *reinterpret_cast<const s16x8*>(Bb + (1 + 32*(ni+4) + col)*8);
        acc[ni] = __builtin_amdgcn_mfma_f32_32x32x16_bf16(a, bfr, acc[ni], 0, 0, 0);
      }
    }
    #pragma unroll
    for (int ni = 0; ni < 4; ++ni)
      #pragma unroll
      for (int r = 0; r < 16; ++r) {
        int crow = 32*wv + (r&3) + 8*(r>>2) + 4*half;
        outb[(size_t)crow*W_DIM + w0 + 32*(ni+4) + col] = acc[ni][r] + bvs[crow];
      }
  }
}

extern "C" void kernel_launch(void* const* d_in, const int* in_sizes, int n_in,
                              void* d_out, int out_size, void* d_ws, size_t ws_size,
                              hipStream_t stream) {
  (void)in_sizes; (void)n_in; (void)out_size; (void)ws_size;
  const float* x  = (const float*)d_in[0];
  const float* Wq = (const float*)d_in[1];
  const float* bq = (const float*)d_in[2];
  const float* Wk = (const float*)d_in[3];
  const float* bk = (const float*)d_in[4];
  const float* Wv = (const float*)d_in[5];
  const float* bv = (const float*)d_in[6];
  float* out = (float*)d_out;
  char* ws = (char*)d_ws;   // needs 264196 B

  hipFuncSetAttribute((const void*)main_kernel,
                      hipFuncAttributeMaxDynamicSharedMemorySize, LDS_BYTES);
  prep_kernel<<<321, 256, 0, stream>>>(Wq, bq, Wk, bk, Wv, ws);
  main_kernel<<<256, 512, LDS_BYTES, stream>>>(x, ws, bv, out);
}

// Round 17
// 81.297 us; speedup vs baseline: 1.1506x; 1.0488x over previous
//
#include <hip/hip_runtime.h>
#include <hip/hip_bf16.h>

#define C_DIM 256
#define W_DIM 4096
#define LDS_BYTES 162528

typedef unsigned short u16;
typedef short s16x8 __attribute__((ext_vector_type(8)));
typedef unsigned short u16x8 __attribute__((ext_vector_type(8)));
typedef unsigned short u16x4 __attribute__((ext_vector_type(4)));
typedef float f32x16 __attribute__((ext_vector_type(16)));

__device__ __forceinline__ u16 f2b(float f) {
  return __builtin_bit_cast(u16, __float2bfloat16(f));
}
__device__ __forceinline__ float b2f(u16 u) {
  return __builtin_bit_cast(float, ((unsigned)u) << 16);
}

// ---------------- prep kernel (unchanged) ----------------
// ws: [0,131072) M bf16 [256][256]; [131072,262144) Wv bf16;
//     [262144) u0[256] f32; [263168) u1[256] f32; [264192) c0 f32
__global__ __launch_bounds__(256) void prep_kernel(
    const float* __restrict__ Wq, const float* __restrict__ bq,
    const float* __restrict__ Wk, const float* __restrict__ bk,
    const float* __restrict__ Wv, char* __restrict__ ws) {
  u16* Mb   = (u16*)ws;
  u16* Wvb  = (u16*)(ws + 131072);
  float* u0 = (float*)(ws + 262144);
  float* u1 = (float*)(ws + 263168);
  float* c0p = (float*)(ws + 264192);
  int bid = blockIdx.x, t = threadIdx.x;
  if (bid < 256) {
    __shared__ float Wqs[256*17];
    __shared__ float Wks[256*17];
    int i0 = (bid >> 4) << 4, j0 = (bid & 15) << 4;
    for (int it = 0; it < 16; ++it) {
      int e = t + 256*it; int a = e >> 4, ii = e & 15;
      Wqs[a*17+ii] = Wq[a*256 + i0 + ii];
      Wks[a*17+ii] = Wk[a*256 + j0 + ii];
    }
    __syncthreads();
    int ii = t >> 4, jj = t & 15;
    float acc = 0.f;
    #pragma unroll 8
    for (int a = 0; a < 256; ++a) acc += Wqs[a*17+ii] * Wks[a*17+jj];
    Mb[(i0+ii)*256 + j0 + jj] = f2b(acc);
  } else if (bid == 256) {
    int j = t;
    float a0 = 0.f, a1 = 0.f;
    #pragma unroll 4
    for (int a = 0; a < 256; ++a) {
      a0 += bq[a] * Wk[a*256 + j];
      a1 += bk[a] * Wq[a*256 + j];
    }
    u0[j] = a0; u1[j] = a1;
    __shared__ float red[256];
    red[t] = bq[t] * bk[t];
    __syncthreads();
    if (t == 0) { float s = 0.f; for (int a = 0; a < 256; ++a) s += red[a]; *c0p = s; }
  } else {
    int base = ((bid - 257)*256 + t) * 4;
    const float4 v = *reinterpret_cast<const float4*>(Wv + base);
    ushort4 pk = make_ushort4(f2b(v.x), f2b(v.y), f2b(v.z), f2b(v.w));
    *reinterpret_cast<ushort4*>(Wvb + base) = pk;
  }
}

// ---------------- main fused kernel ----------------
// 256 blocks = (b 0..15) x (tile 0..15 of 256 out cols). 512 thr (8 waves), 1 blk/CU.
// R12 decomposition (wave = 32 rows x ALL 8 n-tiles, SINGLE pass, acc[8]=128 AGPR)
// de-spilled by replacing the 9th tail tile with the f-pass (f1,f2,f3).
// Total regs ~ 128 AGPR + ~110 VGPR <= 256 -> no scratch.
// LDS 162528 B:
//   Xt  [kk 0..31][j 0..258][e 0..7] bf16  132608 @0
//   Ps  [3][8][258] f32 (PsA a/b overlay planes 0/1)  24768 @132608
//   ABs [2][258] f32                         2064 @157376
//   fS  [4] f32                                16 @159440
//   U   [2][256] f32                         2048 @159456
//   bvs [256] f32                            1024 @161504
__global__ __launch_bounds__(512, 2) void main_kernel(
    const float* __restrict__ x, const char* __restrict__ ws,
    const float* __restrict__ bv, float* __restrict__ out) {
  const u16* Mb   = (const u16*)ws;
  const u16* Wvb  = (const u16*)(ws + 131072);
  const float* u0g = (const float*)(ws + 262144);
  const float* u1g = (const float*)(ws + 263168);
  const float c0  = *(const float*)(ws + 264192);

  extern __shared__ char lds[];
  u16*   Xt  = (u16*)lds;
  float* Ps  = (float*)(lds + 132608);
  float* ABs = (float*)(lds + 157376);
  float* fS  = (float*)(lds + 159440);
  float* U   = (float*)(lds + 159456);
  float* bvs = (float*)(lds + 161504);

  const int bid = blockIdx.x;
  const int t = threadIdx.x;
  const int wv = t >> 6, l = t & 63;
  const int col = l & 31, half = l >> 5;

  const int b  = bid >> 4;
  const int cw = bid & 15;
  const int w0 = cw << 8;
  const float* xb = x + (size_t)b * (C_DIM*W_DIM);
  float* outb = out + (size_t)b * (C_DIM*W_DIM);

  if (t < 4) fS[t] = 0.f;
  if (t < 256) { U[t] = u0g[t]; U[256+t] = u1g[t]; bvs[t] = bv[t]; }
  __syncthreads();

  // ---- P0: stage x -> Xt bf16 (wave-private strips 4wv..4wv+3) + a/b partials ----
  {
    #pragma unroll
    for (int p = 0; p < 4; ++p) {
      int j = 64*p + l;
      int w = w0 - 1 + j;                 // w <= 4094, only lower bound can fail
      bool ok = (w >= 0);
      const float* xp = xb + w;
      float xr[32];
      #pragma unroll
      for (int g = 0; g < 4; ++g)
        #pragma unroll
        for (int e = 0; e < 8; ++e)
          xr[g*8+e] = ok ? xp[(size_t)((4*wv+g)*8 + e) * W_DIM] : 0.f;
      float pa = 0.f, pb_ = 0.f;
      #pragma unroll
      for (int g = 0; g < 4; ++g) {
        int kk = 4*wv + g;
        union { u16 u[8]; u16x8 v; } pk;
        #pragma unroll
        for (int e = 0; e < 8; ++e) {
          float v = xr[g*8+e];
          pk.u[e] = f2b(v);
          pa  += U[kk*8+e] * v;
          pb_ += U[256 + kk*8+e] * v;
        }
        *reinterpret_cast<u16x8*>(Xt + (kk*259 + j)*8) = pk.v;
      }
      Ps[wv*258 + j] = pa;
      Ps[2064 + wv*258 + j] = pb_;
    }
    if (l < 3) {                           // j = 256,257 real; 258 zero pad
      int j = 256 + l;
      int w = w0 - 1 + j;
      bool real = (l < 2) && (w < W_DIM);
      const float* xpe = xb + w;
      float pa = 0.f, pb_ = 0.f;
      #pragma unroll
      for (int g = 0; g < 4; ++g) {
        int kk = 4*wv + g;
        union { u16 u[8]; u16x8 v; } pk;
        #pragma unroll
        for (int e = 0; e < 8; ++e) {
          float v = real ? xpe[(size_t)(kk*8+e) * W_DIM] : 0.f;
          pk.u[e] = f2b(v);
          pa  += U[kk*8+e] * v;
          pb_ += U[256 + kk*8+e] * v;
        }
        *reinterpret_cast<u16x8*>(Xt + (kk*259 + j)*8) = pk.v;
      }
      if (l < 2) {
        Ps[wv*258 + j] = pa;
        Ps[2064 + wv*258 + j] = pb_;
      }
    }
  }
  __syncthreads();   // bar1

  // ---- GEMM1: G = M @ X, SINGLE pass, 8 n-tiles (rows 32wv) ----
  f32x16 acc[8];
  #pragma unroll
  for (int ni = 0; ni < 8; ++ni)
    #pragma unroll
    for (int r = 0; r < 16; ++r) acc[ni][r] = 0.f;
  const u16* Arow1 = Mb + (32*wv + col)*256 + 8*half;
  {
    #pragma unroll
    for (int kk = 0; kk < 16; ++kk) {
      s16x8 a = *reinterpret_cast<const s16x8*>(Arow1 + 16*kk);
      const u16* Bb = Xt + (2*kk + half)*259*8;
      #pragma unroll
      for (int ni = 0; ni < 8; ++ni) {
        s16x8 bfr = *reinterpret_cast<const s16x8*>(Bb + (32*ni + col)*8);
        acc[ni] = __builtin_amdgcn_mfma_f32_32x32x16_bf16(a, bfr, acc[ni], 0, 0, 0);
      }
    }
  }

  // ---- f-pass: f1=x256'Mx256, f2=x256'Mx257, f3=x255'Mx256 (tail scores) ----
  {
    int i = t >> 1, kq = t & 1;
    float xi255 = b2f(Xt[((i>>3)*259 + 255)*8 + (i&7)]);
    float xi256 = b2f(Xt[((i>>3)*259 + 256)*8 + (i&7)]);
    float a1 = 0.f, a2 = 0.f;
    const u16* Mrow = Mb + i*256 + 128*kq;
    #pragma unroll
    for (int kk8 = 0; kk8 < 16; ++kk8) {
      int sA = 16*kq + kk8;
      s16x8 m8 = *reinterpret_cast<const s16x8*>(Mrow + 8*kk8);
      u16x8 xk6 = *reinterpret_cast<const u16x8*>(Xt + (sA*259 + 256)*8);
      u16x8 xk7 = *reinterpret_cast<const u16x8*>(Xt + (sA*259 + 257)*8);
      #pragma unroll
      for (int e = 0; e < 8; ++e) {
        float m = b2f((u16)m8[e]);
        a1 += m * b2f(xk6[e]);
        a2 += m * b2f(xk7[e]);
      }
    }
    float p1 = xi256*a1, p2 = xi256*a2, p3 = xi255*a1;
    #pragma unroll
    for (int d = 1; d < 64; d <<= 1) {
      p1 += __shfl_xor(p1, d); p2 += __shfl_xor(p2, d); p3 += __shfl_xor(p3, d);
    }
    if (l == 0) { atomicAdd(&fS[0], p1); atomicAdd(&fS[1], p2); atomicAdd(&fS[2], p3); }
  }
  // alpha/beta reduce (PsA complete since bar1)
  for (int i = t; i < 516; i += 512) {
    int which = (i >= 258) ? 1 : 0;
    int jj = i - 258*which;
    float s = 0.f;
    #pragma unroll
    for (int g = 0; g < 8; ++g) s += Ps[which*2064 + g*258 + jj];
    ABs[which*258 + jj] = s;
  }
  __syncthreads();   // bar2: Ps transitions PsA -> PsB

  // ---- P2: score partials from acc (all 8 n-tiles) -> PsB ----
  {
    #pragma unroll
    for (int ni = 0; ni < 8; ++ni) {
      int jt = 32*ni + col;                // 0..255
      int jm = (jt > 0) ? jt-1 : 0;
      int jp = jt + 1;                     // <= 256
      float s0 = 0.f, s1 = 0.f, s2 = 0.f;
      #pragma unroll
      for (int q = 0; q < 4; ++q) {
        const u16* base = Xt + (4*wv + q)*259*8 + 4*half;
        u16x4 xm = *reinterpret_cast<const u16x4*>(base + jm*8);
        u16x4 xc = *reinterpret_cast<const u16x4*>(base + jt*8);
        u16x4 xp = *reinterpret_cast<const u16x4*>(base + jp*8);
        #pragma unroll
        for (int r4 = 0; r4 < 4; ++r4) {
          float g0 = acc[ni][4*q + r4];
          s2 += g0 * b2f(xm[r4]);
          s1 += g0 * b2f(xc[r4]);
          s0 += g0 * b2f(xp[r4]);
        }
      }
      s0 += __shfl_xor(s0, 32);
      s1 += __shfl_xor(s1, 32);
      s2 += __shfl_xor(s2, 32);
      if (half == 0) {
        Ps[0*2064 + wv*258 + jt+1] = s0;
        if (jt >= 1) Ps[1*2064 + wv*258 + jt]   = s1;
        if (jt >= 2) Ps[2*2064 + wv*258 + jt-1] = s2;
      }
    }
  }
  __syncthreads();   // bar3

  // ---- softmax (oc = 64p+l) + in-place mix of own 4 strips ----
  {
    float aw0[4], aw1[4], aw2[4];
    #pragma unroll
    for (int p = 0; p < 4; ++p) {
      int oc = 64*p + l;
      int jp = oc + 1;
      float d0 = 0.f, d1 = 0.f, d2 = 0.f;
      #pragma unroll
      for (int g = 0; g < 8; ++g) {
        d0 += Ps[0*2064 + g*258 + jp];
        d1 += Ps[1*2064 + g*258 + jp];
        d2 += Ps[2*2064 + g*258 + jp];
      }
      if (oc == 255)      { d1 = fS[0]; d2 = fS[1]; }
      else if (oc == 254) { d2 = fS[2]; }
      float am = ABs[jp-1], ac_ = ABs[jp], ap_ = ABs[jp+1];
      float be = ABs[258 + jp];
      float sc0 = (d0 + am + be + c0) * 0.0625f;
      float sc1 = (d1 + ac_ + be + c0) * 0.0625f;
      float sc2 = (d2 + ap_ + be + c0) * 0.0625f;
      int w = w0 + oc;
      bool v0 = (w >= 1), v2 = (w + 1 < W_DIM);
      const float NEG = -1e30f;
      float m = fmaxf(v0 ? sc0 : NEG, fmaxf(sc1, v2 ? sc2 : NEG));
      float e0v = v0 ? __expf(sc0 - m) : 0.f;
      float e1v = __expf(sc1 - m);
      float e2v = v2 ? __expf(sc2 - m) : 0.f;
      float inv = 1.f / (e0v + e1v + e2v);
      aw0[p] = e0v*inv; aw1[p] = e1v*inv; aw2[p] = e2v*inv;
    }
    #pragma unroll
    for (int g = 0; g < 4; ++g) {
      u16* base = Xt + (4*wv + g)*259*8;
      u16x8 xrd[12];
      #pragma unroll
      for (int p = 0; p < 4; ++p)
        #pragma unroll
        for (int i = 0; i < 3; ++i)
          xrd[p*3+i] = *reinterpret_cast<const u16x8*>(base + (64*p + l + i)*8);
      __builtin_amdgcn_sched_barrier(0);
      #pragma unroll
      for (int p = 0; p < 4; ++p) {
        union { u16 u[8]; u16x8 v; } pk;
        #pragma unroll
        for (int e = 0; e < 8; ++e)
          pk.u[e] = f2b(aw0[p]*b2f(xrd[p*3][e]) + aw1[p]*b2f(xrd[p*3+1][e])
                        + aw2[p]*b2f(xrd[p*3+2][e]));
        *reinterpret_cast<u16x8*>(base + (64*p + l + 1)*8) = pk.v;
      }
      __builtin_amdgcn_sched_barrier(0);
    }
  }
  __syncthreads();   // bar4

  // ---- GEMM2: out = Wv @ Xmix + bv, SINGLE pass, 8 n-tiles, dense stores ----
  {
    #pragma unroll
    for (int ni = 0; ni < 8; ++ni)
      #pragma unroll
      for (int r = 0; r < 16; ++r) acc[ni][r] = 0.f;
    const u16* Arow2 = Wvb + (32*wv + col)*256 + 8*half;
    #pragma unroll
    for (int kk = 0; kk < 16; ++kk) {
      s16x8 a = *reinterpret_cast<const s16x8*>(Arow2 + 16*kk);
      const u16* Bb = Xt + (2*kk + half)*259*8;
      #pragma unroll
      for (int ni = 0; ni < 8; ++ni) {
        s16x8 bfr = *reinterpret_cast<const s16x8*>(Bb + (1 + 32*ni + col)*8);
        acc[ni] = __builtin_amdgcn_mfma_f32_32x32x16_bf16(a, bfr, acc[ni], 0, 0, 0);
      }
    }
    #pragma unroll
    for (int ni = 0; ni < 8; ++ni)
      #pragma unroll
      for (int r = 0; r < 16; ++r) {
        int crow = 32*wv + (r&3) + 8*(r>>2) + 4*half;
        outb[(size_t)crow*W_DIM + w0 + 32*ni + col] = acc[ni][r] + bvs[crow];
      }
  }
}

extern "C" void kernel_launch(void* const* d_in, const int* in_sizes, int n_in,
                              void* d_out, int out_size, void* d_ws, size_t ws_size,
                              hipStream_t stream) {
  (void)in_sizes; (void)n_in; (void)out_size; (void)ws_size;
  const float* x  = (const float*)d_in[0];
  const float* Wq = (const float*)d_in[1];
  const float* bq = (const float*)d_in[2];
  const float* Wk = (const float*)d_in[3];
  const float* bk = (const float*)d_in[4];
  const float* Wv = (const float*)d_in[5];
  const float* bv = (const float*)d_in[6];
  float* out = (float*)d_out;
  char* ws = (char*)d_ws;   // needs 264196 B

  hipFuncSetAttribute((const void*)main_kernel,
                      hipFuncAttributeMaxDynamicSharedMemorySize, LDS_BYTES);
  prep_kernel<<<321, 256, 0, stream>>>(Wq, bq, Wk, bk, Wv, ws);
  main_kernel<<<256, 512, LDS_BYTES, stream>>>(x, ws, bv, out);
}

// Round 18
// 80.436 us; speedup vs baseline: 1.1629x; 1.0107x over previous
//
#include <hip/hip_runtime.h>
#include <hip/hip_bf16.h>

#define C_DIM 256
#define W_DIM 4096
#define LDS_BYTES 162528

typedef unsigned short u16;
typedef short s16x8 __attribute__((ext_vector_type(8)));
typedef unsigned short u16x8 __attribute__((ext_vector_type(8)));
typedef unsigned short u16x4 __attribute__((ext_vector_type(4)));
typedef float f32x16 __attribute__((ext_vector_type(16)));
typedef float f32x4 __attribute__((ext_vector_type(4)));

__device__ __forceinline__ u16 f2b(float f) {
  return __builtin_bit_cast(u16, __float2bfloat16(f));
}
__device__ __forceinline__ float b2f(u16 u) {
  return __builtin_bit_cast(float, ((unsigned)u) << 16);
}

// ---------------- prep kernel (unchanged) ----------------
// ws: [0,131072) M bf16 [256][256]; [131072,262144) Wv bf16;
//     [262144) u0[256] f32; [263168) u1[256] f32; [264192) c0 f32
__global__ __launch_bounds__(256) void prep_kernel(
    const float* __restrict__ Wq, const float* __restrict__ bq,
    const float* __restrict__ Wk, const float* __restrict__ bk,
    const float* __restrict__ Wv, char* __restrict__ ws) {
  u16* Mb   = (u16*)ws;
  u16* Wvb  = (u16*)(ws + 131072);
  float* u0 = (float*)(ws + 262144);
  float* u1 = (float*)(ws + 263168);
  float* c0p = (float*)(ws + 264192);
  int bid = blockIdx.x, t = threadIdx.x;
  if (bid < 256) {
    __shared__ float Wqs[256*17];
    __shared__ float Wks[256*17];
    int i0 = (bid >> 4) << 4, j0 = (bid & 15) << 4;
    for (int it = 0; it < 16; ++it) {
      int e = t + 256*it; int a = e >> 4, ii = e & 15;
      Wqs[a*17+ii] = Wq[a*256 + i0 + ii];
      Wks[a*17+ii] = Wk[a*256 + j0 + ii];
    }
    __syncthreads();
    int ii = t >> 4, jj = t & 15;
    float acc = 0.f;
    #pragma unroll 8
    for (int a = 0; a < 256; ++a) acc += Wqs[a*17+ii] * Wks[a*17+jj];
    Mb[(i0+ii)*256 + j0 + jj] = f2b(acc);
  } else if (bid == 256) {
    int j = t;
    float a0 = 0.f, a1 = 0.f;
    #pragma unroll 4
    for (int a = 0; a < 256; ++a) {
      a0 += bq[a] * Wk[a*256 + j];
      a1 += bk[a] * Wq[a*256 + j];
    }
    u0[j] = a0; u1[j] = a1;
    __shared__ float red[256];
    red[t] = bq[t] * bk[t];
    __syncthreads();
    if (t == 0) { float s = 0.f; for (int a = 0; a < 256; ++a) s += red[a]; *c0p = s; }
  } else {
    int base = ((bid - 257)*256 + t) * 4;
    const float4 v = *reinterpret_cast<const float4*>(Wv + base);
    ushort4 pk = make_ushort4(f2b(v.x), f2b(v.y), f2b(v.z), f2b(v.w));
    *reinterpret_cast<ushort4*>(Wvb + base) = pk;
  }
}

// ---------------- main fused kernel ----------------
// 256 blocks = (b 0..15) x (tile 0..15 of 256 out cols). 512 thr (8 waves), 1 blk/CU.
// R12 decomposition (wave = 32 rows x ALL 8 n-tiles, SINGLE pass, acc[8]=128 AGPR).
// Tail G-cols 256/257 via TWO 16x16x32 MFMA tiles (8 AGPR) -> f1,f2,f3;
// total acc = 136 regs, VGPR <= 120 -> no spill, full ILP.
// LDS 162528 B:
//   Xt  [kk 0..31][j 0..258][e 0..7] bf16  132608 @0
//   Ps  [3][8][258] f32 (PsA a/b overlay planes 0/1)  24768 @132608
//   ABs [2][258] f32                         2064 @157376
//   fS  [4] f32                                16 @159440
//   U   [2][256] f32                         2048 @159456
//   bvs [256] f32                            1024 @161504
__global__ __launch_bounds__(512, 2) void main_kernel(
    const float* __restrict__ x, const char* __restrict__ ws,
    const float* __restrict__ bv, float* __restrict__ out) {
  const u16* Mb   = (const u16*)ws;
  const u16* Wvb  = (const u16*)(ws + 131072);
  const float* u0g = (const float*)(ws + 262144);
  const float* u1g = (const float*)(ws + 263168);
  const float c0  = *(const float*)(ws + 264192);

  extern __shared__ char lds[];
  u16*   Xt  = (u16*)lds;
  float* Ps  = (float*)(lds + 132608);
  float* ABs = (float*)(lds + 157376);
  float* fS  = (float*)(lds + 159440);
  float* U   = (float*)(lds + 159456);
  float* bvs = (float*)(lds + 161504);

  const int bid = blockIdx.x;
  const int t = threadIdx.x;
  const int wv = t >> 6, l = t & 63;
  const int col = l & 31, half = l >> 5;

  const int b  = bid >> 4;
  const int cw = bid & 15;
  const int w0 = cw << 8;
  const float* xb = x + (size_t)b * (C_DIM*W_DIM);
  float* outb = out + (size_t)b * (C_DIM*W_DIM);

  if (t < 4) fS[t] = 0.f;
  if (t < 256) { U[t] = u0g[t]; U[256+t] = u1g[t]; bvs[t] = bv[t]; }
  __syncthreads();

  // ---- P0: stage x -> Xt bf16 (wave-private strips 4wv..4wv+3) + a/b partials ----
  {
    #pragma unroll
    for (int p = 0; p < 4; ++p) {
      int j = 64*p + l;
      int w = w0 - 1 + j;                 // w <= 4094, only lower bound can fail
      bool ok = (w >= 0);
      const float* xp = xb + w;
      float xr[32];
      #pragma unroll
      for (int g = 0; g < 4; ++g)
        #pragma unroll
        for (int e = 0; e < 8; ++e)
          xr[g*8+e] = ok ? xp[(size_t)((4*wv+g)*8 + e) * W_DIM] : 0.f;
      float pa = 0.f, pb_ = 0.f;
      #pragma unroll
      for (int g = 0; g < 4; ++g) {
        int kk = 4*wv + g;
        union { u16 u[8]; u16x8 v; } pk;
        #pragma unroll
        for (int e = 0; e < 8; ++e) {
          float v = xr[g*8+e];
          pk.u[e] = f2b(v);
          pa  += U[kk*8+e] * v;
          pb_ += U[256 + kk*8+e] * v;
        }
        *reinterpret_cast<u16x8*>(Xt + (kk*259 + j)*8) = pk.v;
      }
      Ps[wv*258 + j] = pa;
      Ps[2064 + wv*258 + j] = pb_;
    }
    if (l < 3) {                           // j = 256,257 real; 258 zero pad
      int j = 256 + l;
      int w = w0 - 1 + j;
      bool real = (l < 2) && (w < W_DIM);
      const float* xpe = xb + w;
      float pa = 0.f, pb_ = 0.f;
      #pragma unroll
      for (int g = 0; g < 4; ++g) {
        int kk = 4*wv + g;
        union { u16 u[8]; u16x8 v; } pk;
        #pragma unroll
        for (int e = 0; e < 8; ++e) {
          float v = real ? xpe[(size_t)(kk*8+e) * W_DIM] : 0.f;
          pk.u[e] = f2b(v);
          pa  += U[kk*8+e] * v;
          pb_ += U[256 + kk*8+e] * v;
        }
        *reinterpret_cast<u16x8*>(Xt + (kk*259 + j)*8) = pk.v;
      }
      if (l < 2) {
        Ps[wv*258 + j] = pa;
        Ps[2064 + wv*258 + j] = pb_;
      }
    }
  }
  __syncthreads();   // bar1

  // ---- GEMM1: G = M @ X, SINGLE pass, 8 n-tiles (rows 32wv) ----
  f32x16 acc[8];
  #pragma unroll
  for (int ni = 0; ni < 8; ++ni)
    #pragma unroll
    for (int r = 0; r < 16; ++r) acc[ni][r] = 0.f;
  const u16* Arow1 = Mb + (32*wv + col)*256 + 8*half;
  {
    #pragma unroll
    for (int kk = 0; kk < 16; ++kk) {
      s16x8 a = *reinterpret_cast<const s16x8*>(Arow1 + 16*kk);
      const u16* Bb = Xt + (2*kk + half)*259*8;
      #pragma unroll
      for (int ni = 0; ni < 8; ++ni) {
        s16x8 bfr = *reinterpret_cast<const s16x8*>(Bb + (32*ni + col)*8);
        acc[ni] = __builtin_amdgcn_mfma_f32_32x32x16_bf16(a, bfr, acc[ni], 0, 0, 0);
      }
    }
  }

  // ---- GEMM1-tail: G cols 256/257 via two 16x16x32 tiles (rows 32wv+16tt) ----
  // 16x16x32 layouts: A row = l&15, k = 32st + 8*(l>>4)+e; B col = l&15, same k;
  // C/D: col = l&15, row = (l>>4)*4 + r  [HW-verified mapping].
  f32x4 acct[2];
  #pragma unroll
  for (int tt = 0; tt < 2; ++tt)
    #pragma unroll
    for (int r = 0; r < 4; ++r) acct[tt][r] = 0.f;
  {
    const int ra = l & 15, kg = l >> 4;
    #pragma unroll
    for (int st = 0; st < 8; ++st) {
      // B col = 256+ra (ra>=3 reads junk cols -> isolated, unused C cols)
      s16x8 bfr = *reinterpret_cast<const s16x8*>(
          Xt + ((4*st + kg)*259 + 256 + ra)*8);
      #pragma unroll
      for (int tt = 0; tt < 2; ++tt) {
        s16x8 a = *reinterpret_cast<const s16x8*>(
            Mb + (32*wv + 16*tt + ra)*256 + 32*st + 8*kg);
        acct[tt] = __builtin_amdgcn_mfma_f32_16x16x32_bf16(a, bfr, acct[tt], 0, 0, 0);
      }
    }
  }

  // alpha/beta reduce (PsA complete since bar1)
  for (int i = t; i < 516; i += 512) {
    int which = (i >= 258) ? 1 : 0;
    int jj = i - 258*which;
    float s = 0.f;
    #pragma unroll
    for (int g = 0; g < 8; ++g) s += Ps[which*2064 + g*258 + jj];
    ABs[which*258 + jj] = s;
  }
  __syncthreads();   // bar2: Ps transitions PsA -> PsB

  // ---- P2: score partials from acc (all 8 n-tiles) -> PsB ----
  {
    #pragma unroll
    for (int ni = 0; ni < 8; ++ni) {
      int jt = 32*ni + col;                // 0..255
      int jm = (jt > 0) ? jt-1 : 0;
      int jp = jt + 1;                     // <= 256
      float s0 = 0.f, s1 = 0.f, s2 = 0.f;
      #pragma unroll
      for (int q = 0; q < 4; ++q) {
        const u16* base = Xt + (4*wv + q)*259*8 + 4*half;
        u16x4 xm = *reinterpret_cast<const u16x4*>(base + jm*8);
        u16x4 xc = *reinterpret_cast<const u16x4*>(base + jt*8);
        u16x4 xp = *reinterpret_cast<const u16x4*>(base + jp*8);
        #pragma unroll
        for (int r4 = 0; r4 < 4; ++r4) {
          float g0 = acc[ni][4*q + r4];
          s2 += g0 * b2f(xm[r4]);
          s1 += g0 * b2f(xc[r4]);
          s0 += g0 * b2f(xp[r4]);
        }
      }
      s0 += __shfl_xor(s0, 32);
      s1 += __shfl_xor(s1, 32);
      s2 += __shfl_xor(s2, 32);
      if (half == 0) {
        Ps[0*2064 + wv*258 + jt+1] = s0;
        if (jt >= 1) Ps[1*2064 + wv*258 + jt]   = s1;
        if (jt >= 2) Ps[2*2064 + wv*258 + jt-1] = s2;
      }
    }
  }

  // ---- P2-tail: f1=x256.g256, f2=x256.g257, f3=x255.g256 from acct ----
  {
    const int j16 = l & 15, lg = l >> 4;
    float p1 = 0.f, p2 = 0.f, p3 = 0.f;
    if (j16 < 2) {
      #pragma unroll
      for (int tt = 0; tt < 2; ++tt)
        #pragma unroll
        for (int r = 0; r < 4; ++r) {
          int i = 32*wv + 16*tt + lg*4 + r;
          float g = acct[tt][r];
          float x6 = b2f(Xt[((i>>3)*259 + 256)*8 + (i&7)]);
          if (j16 == 0) {
            float x5 = b2f(Xt[((i>>3)*259 + 255)*8 + (i&7)]);
            p1 += x6 * g; p3 += x5 * g;
          } else {
            p2 += x6 * g;
          }
        }
    }
    p1 += __shfl_xor(p1, 16); p1 += __shfl_xor(p1, 32);
    p3 += __shfl_xor(p3, 16); p3 += __shfl_xor(p3, 32);
    p2 += __shfl_xor(p2, 16); p2 += __shfl_xor(p2, 32);
    if (l == 0) { atomicAdd(&fS[0], p1); atomicAdd(&fS[2], p3); }
    if (l == 1) atomicAdd(&fS[1], p2);
  }
  __syncthreads();   // bar3

  // ---- softmax (oc = 64p+l) + in-place mix of own 4 strips ----
  {
    float aw0[4], aw1[4], aw2[4];
    #pragma unroll
    for (int p = 0; p < 4; ++p) {
      int oc = 64*p + l;
      int jp = oc + 1;
      float d0 = 0.f, d1 = 0.f, d2 = 0.f;
      #pragma unroll
      for (int g = 0; g < 8; ++g) {
        d0 += Ps[0*2064 + g*258 + jp];
        d1 += Ps[1*2064 + g*258 + jp];
        d2 += Ps[2*2064 + g*258 + jp];
      }
      if (oc == 255)      { d1 = fS[0]; d2 = fS[1]; }
      else if (oc == 254) { d2 = fS[2]; }
      float am = ABs[jp-1], ac_ = ABs[jp], ap_ = ABs[jp+1];
      float be = ABs[258 + jp];
      float sc0 = (d0 + am + be + c0) * 0.0625f;
      float sc1 = (d1 + ac_ + be + c0) * 0.0625f;
      float sc2 = (d2 + ap_ + be + c0) * 0.0625f;
      int w = w0 + oc;
      bool v0 = (w >= 1), v2 = (w + 1 < W_DIM);
      const float NEG = -1e30f;
      float m = fmaxf(v0 ? sc0 : NEG, fmaxf(sc1, v2 ? sc2 : NEG));
      float e0v = v0 ? __expf(sc0 - m) : 0.f;
      float e1v = __expf(sc1 - m);
      float e2v = v2 ? __expf(sc2 - m) : 0.f;
      float inv = 1.f / (e0v + e1v + e2v);
      aw0[p] = e0v*inv; aw1[p] = e1v*inv; aw2[p] = e2v*inv;
    }
    #pragma unroll
    for (int g = 0; g < 4; ++g) {
      u16* base = Xt + (4*wv + g)*259*8;
      u16x8 xrd[12];
      #pragma unroll
      for (int p = 0; p < 4; ++p)
        #pragma unroll
        for (int i = 0; i < 3; ++i)
          xrd[p*3+i] = *reinterpret_cast<const u16x8*>(base + (64*p + l + i)*8);
      __builtin_amdgcn_sched_barrier(0);
      #pragma unroll
      for (int p = 0; p < 4; ++p) {
        union { u16 u[8]; u16x8 v; } pk;
        #pragma unroll
        for (int e = 0; e < 8; ++e)
          pk.u[e] = f2b(aw0[p]*b2f(xrd[p*3][e]) + aw1[p]*b2f(xrd[p*3+1][e])
                        + aw2[p]*b2f(xrd[p*3+2][e]));
        *reinterpret_cast<u16x8*>(base + (64*p + l + 1)*8) = pk.v;
      }
      __builtin_amdgcn_sched_barrier(0);
    }
  }
  __syncthreads();   // bar4

  // ---- GEMM2: out = Wv @ Xmix + bv, SINGLE pass, 8 n-tiles, dense stores ----
  {
    #pragma unroll
    for (int ni = 0; ni < 8; ++ni)
      #pragma unroll
      for (int r = 0; r < 16; ++r) acc[ni][r] = 0.f;
    const u16* Arow2 = Wvb + (32*wv + col)*256 + 8*half;
    #pragma unroll
    for (int kk = 0; kk < 16; ++kk) {
      s16x8 a = *reinterpret_cast<const s16x8*>(Arow2 + 16*kk);
      const u16* Bb = Xt + (2*kk + half)*259*8;
      #pragma unroll
      for (int ni = 0; ni < 8; ++ni) {
        s16x8 bfr = *reinterpret_cast<const s16x8*>(Bb + (1 + 32*ni + col)*8);
        acc[ni] = __builtin_amdgcn_mfma_f32_32x32x16_bf16(a, bfr, acc[ni], 0, 0, 0);
      }
    }
    #pragma unroll
    for (int ni = 0; ni < 8; ++ni)
      #pragma unroll
      for (int r = 0; r < 16; ++r) {
        int crow = 32*wv + (r&3) + 8*(r>>2) + 4*half;
        outb[(size_t)crow*W_DIM + w0 + 32*ni + col] = acc[ni][r] + bvs[crow];
      }
  }
}

extern "C" void kernel_launch(void* const* d_in, const int* in_sizes, int n_in,
                              void* d_out, int out_size, void* d_ws, size_t ws_size,
                              hipStream_t stream) {
  (void)in_sizes; (void)n_in; (void)out_size; (void)ws_size;
  const float* x  = (const float*)d_in[0];
  const float* Wq = (const float*)d_in[1];
  const float* bq = (const float*)d_in[2];
  const float* Wk = (const float*)d_in[3];
  const float* bk = (const float*)d_in[4];
  const float* Wv = (const float*)d_in[5];
  const float* bv = (const float*)d_in[6];
  float* out = (float*)d_out;
  char* ws = (char*)d_ws;   // needs 264196 B

  hipFuncSetAttribute((const void*)main_kernel,
                      hipFuncAttributeMaxDynamicSharedMemorySize, LDS_BYTES);
  prep_kernel<<<321, 256, 0, stream>>>(Wq, bq, Wk, bk, Wv, ws);
  main_kernel<<<256, 512, LDS_BYTES, stream>>>(x, ws, bv, out);
}

// Round 19
// 78.435 us; speedup vs baseline: 1.1925x; 1.0255x over previous
//
#include <hip/hip_runtime.h>
#include <hip/hip_bf16.h>

#define C_DIM 256
#define W_DIM 4096
#define LDS_BYTES 162512

typedef unsigned short u16;
typedef short s16x8 __attribute__((ext_vector_type(8)));
typedef unsigned short u16x8 __attribute__((ext_vector_type(8)));
typedef unsigned short u16x4 __attribute__((ext_vector_type(4)));
typedef float f32x16 __attribute__((ext_vector_type(16)));

__device__ __forceinline__ u16 f2b(float f) {
  return __builtin_bit_cast(u16, __float2bfloat16(f));
}
__device__ __forceinline__ float b2f(u16 u) {
  return __builtin_bit_cast(float, ((unsigned)u) << 16);
}

// ---------------- prep kernel ----------------
// ws: [0,131072) M bf16 [256][256]; [131072,262144) Wv bf16;
//     [262144) u0[256] f32; [263168) u1[256] f32; [264192) c0 f32
__global__ __launch_bounds__(256) void prep_kernel(
    const float* __restrict__ Wq, const float* __restrict__ bq,
    const float* __restrict__ Wk, const float* __restrict__ bk,
    const float* __restrict__ Wv, char* __restrict__ ws) {
  u16* Mb   = (u16*)ws;
  u16* Wvb  = (u16*)(ws + 131072);
  float* u0 = (float*)(ws + 262144);
  float* u1 = (float*)(ws + 263168);
  float* c0p = (float*)(ws + 264192);
  int bid = blockIdx.x, t = threadIdx.x;
  if (bid < 256) {
    __shared__ float Wqs[256*17];
    __shared__ float Wks[256*17];
    int i0 = (bid >> 4) << 4, j0 = (bid & 15) << 4;
    for (int it = 0; it < 16; ++it) {
      int e = t + 256*it; int a = e >> 4, ii = e & 15;
      Wqs[a*17+ii] = Wq[a*256 + i0 + ii];
      Wks[a*17+ii] = Wk[a*256 + j0 + ii];
    }
    __syncthreads();
    int ii = t >> 4, jj = t & 15;
    float acc = 0.f;
    #pragma unroll 8
    for (int a = 0; a < 256; ++a) acc += Wqs[a*17+ii] * Wks[a*17+jj];
    Mb[(i0+ii)*256 + j0 + jj] = f2b(acc);
  } else if (bid == 256) {
    int j = t;
    float a0 = 0.f, a1 = 0.f;
    #pragma unroll 4
    for (int a = 0; a < 256; ++a) {
      a0 += bq[a] * Wk[a*256 + j];
      a1 += bk[a] * Wq[a*256 + j];
    }
    u0[j] = a0; u1[j] = a1;
    __shared__ float red[256];
    red[t] = bq[t] * bk[t];
    __syncthreads();
    if (t == 0) { float s = 0.f; for (int a = 0; a < 256; ++a) s += red[a]; *c0p = s; }
  } else {
    int base = ((bid - 257)*256 + t) * 4;
    const float4 v = *reinterpret_cast<const float4*>(Wv + base);
    ushort4 pk = make_ushort4(f2b(v.x), f2b(v.y), f2b(v.z), f2b(v.w));
    *reinterpret_cast<ushort4*>(Wvb + base) = pk;
  }
}

// ---------------- main fused kernel ----------------
// 256 blocks = (b 0..15) x (tile 0..15 of 256 out cols). 512 thr, 1 block/CU.
// j = 0..257 <-> w = w0-1+j; out col oc = 0..255 <-> w = w0+oc (j' = oc+1).
// LDS 162512 B:
//   Xt  [kk 0..31][j 0..258][e 0..7] bf16   132608 @0     (col 258 = zero pad)
//   Ps  [3][8][258] f32 (PsA 2x overlays)    24768 @132608
//   ABs [2][258] f32                          2064 @157376
//   U   [2][256] f32                          2048 @159440
//   bvs [256] f32                             1024 @161488
__global__ __launch_bounds__(512, 2) void main_kernel(
    const float* __restrict__ x, const char* __restrict__ ws,
    const float* __restrict__ bv, float* __restrict__ out) {
  const u16* Mb   = (const u16*)ws;
  const u16* Wvb  = (const u16*)(ws + 131072);
  const float* u0g = (const float*)(ws + 262144);
  const float* u1g = (const float*)(ws + 263168);
  const float c0  = *(const float*)(ws + 264192);

  extern __shared__ char lds[];
  u16*   Xt  = (u16*)lds;
  float* Ps  = (float*)(lds + 132608);
  float* ABs = (float*)(lds + 157376);
  float* U   = (float*)(lds + 159440);
  float* bvs = (float*)(lds + 161488);

  const int bid = blockIdx.x;
  const int t = threadIdx.x;
  const int wv = t >> 6, l = t & 63;
  const int col = l & 31, half = l >> 5;

  const int b  = bid >> 4;
  const int cw = bid & 15;
  const int w0 = cw << 8;
  const float* xb = x + (size_t)b * (C_DIM*W_DIM);
  float* outb = out + (size_t)b * (C_DIM*W_DIM);

  if (t < 256) { U[t] = u0g[t]; U[256+t] = u1g[t]; bvs[t] = bv[t]; }
  __syncthreads();

  // ---- P0: stage x -> Xt bf16 (wave-private kk strips) + alpha/beta partials ----
  {
    #pragma unroll
    for (int p = 0; p < 4; ++p) {
      int j = 64*p + l;
      int w = w0 - 1 + j;                 // w <= w0+254 always in range
      bool ok = (w >= 0);
      const float* xp = xb + w;
      float xr[32];
      #pragma unroll
      for (int g = 0; g < 4; ++g)
        #pragma unroll
        for (int e = 0; e < 8; ++e)
          xr[g*8+e] = ok ? xp[(size_t)((4*wv+g)*8 + e) * W_DIM] : 0.f;
      float pa = 0.f, pb_ = 0.f;
      #pragma unroll
      for (int g = 0; g < 4; ++g) {
        int kk = 4*wv + g;
        union { u16 u[8]; u16x8 v; } pk;
        #pragma unroll
        for (int e = 0; e < 8; ++e) {
          float v = xr[g*8+e];
          pk.u[e] = f2b(v);
          pa  += U[kk*8+e] * v;
          pb_ += U[256 + kk*8+e] * v;
        }
        *reinterpret_cast<u16x8*>(Xt + (kk*259 + j)*8) = pk.v;
      }
      Ps[wv*258 + j] = pa;
      Ps[2064 + wv*258 + j] = pb_;
    }
    if (l < 3) {                           // j = 256,257 real; 258 zero pad
      int j = 256 + l;
      int w = w0 - 1 + j;
      bool real = (l < 2) && (w < W_DIM);
      const float* xpe = xb + w;
      float pa = 0.f, pb_ = 0.f;
      #pragma unroll
      for (int g = 0; g < 4; ++g) {
        int kk = 4*wv + g;
        union { u16 u[8]; u16x8 v; } pk;
        #pragma unroll
        for (int e = 0; e < 8; ++e) {
          float v = real ? xpe[(size_t)(kk*8+e) * W_DIM] : 0.f;
          pk.u[e] = f2b(v);
          pa  += U[kk*8+e] * v;
          pb_ += U[256 + kk*8+e] * v;
        }
        *reinterpret_cast<u16x8*>(Xt + (kk*259 + j)*8) = pk.v;
      }
      if (l < 2) {
        Ps[wv*258 + j] = pa;
        Ps[2064 + wv*258 + j] = pb_;
      }
    }
  }
  __syncthreads();   // bar1

  // ---- GEMM1: G = M @ X, 9 n-tiles (j = 32n+col; tile 8: j=256+col clamp->pad) ----
  f32x16 acc[9];
  #pragma unroll
  for (int n = 0; n < 9; ++n)
    #pragma unroll
    for (int r = 0; r < 16; ++r) acc[n][r] = 0.f;
  {
    int j8 = 256 + col; if (j8 > 258) j8 = 258;
    const u16* Arow = Mb + (32*wv + col)*256 + 8*half;
    #pragma unroll
    for (int kk = 0; kk < 16; ++kk) {
      s16x8 a = *reinterpret_cast<const s16x8*>(Arow + 16*kk);
      const u16* Bb = Xt + (2*kk + half)*259*8;
      #pragma unroll
      for (int n = 0; n < 8; ++n) {
        s16x8 bfr = *reinterpret_cast<const s16x8*>(Bb + (32*n + col)*8);
        acc[n] = __builtin_amdgcn_mfma_f32_32x32x16_bf16(a, bfr, acc[n], 0, 0, 0);
      }
      s16x8 bfr8 = *reinterpret_cast<const s16x8*>(Bb + j8*8);
      acc[8] = __builtin_amdgcn_mfma_f32_32x32x16_bf16(a, bfr8, acc[8], 0, 0, 0);
    }
  }
  // alpha/beta reduce (PsA consumed here)
  for (int i = t; i < 516; i += 512) {
    int which = (i >= 258) ? 1 : 0;
    int jj = i - 258*which;
    float s = 0.f;
    #pragma unroll
    for (int g = 0; g < 8; ++g) s += Ps[which*2064 + g*258 + jj];
    ABs[which*258 + jj] = s;
  }
  __syncthreads();   // bar2: Ps transitions PsA -> PsB

  // ---- P2: score partials from acc -> PsB ----
  // g col jt feeds: s1 -> D0(jt), s0 -> D-1(jt+1), s2 -> D+1(jt-1)
  {
    #pragma unroll
    for (int n = 0; n < 9; ++n) {
      int jt = (n < 8) ? (32*n + col) : (256 + col);
      int jm = jt - 1; if (jm < 0) jm = 0; if (jm > 258) jm = 258;
      int jc = (jt > 258) ? 258 : jt;
      int jp_ = jt + 1; if (jp_ > 258) jp_ = 258;
      float s0 = 0.f, s1 = 0.f, s2 = 0.f;
      #pragma unroll
      for (int q = 0; q < 4; ++q) {
        const u16* base = Xt + (4*wv + q)*259*8 + 4*half;
        u16x4 xm = *reinterpret_cast<const u16x4*>(base + jm*8);
        u16x4 xc = *reinterpret_cast<const u16x4*>(base + jc*8);
        u16x4 xp = *reinterpret_cast<const u16x4*>(base + jp_*8);
        #pragma unroll
        for (int r4 = 0; r4 < 4; ++r4) {
          float g0 = acc[n][4*q + r4];
          s2 += g0 * b2f(xm[r4]);
          s1 += g0 * b2f(xc[r4]);
          s0 += g0 * b2f(xp[r4]);
        }
      }
      s0 += __shfl_xor(s0, 32);
      s1 += __shfl_xor(s1, 32);
      s2 += __shfl_xor(s2, 32);
      if (half == 0) {
        if (jt <= 255)             Ps[0*2064 + wv*258 + jt+1] = s0;
        if (jt >= 1 && jt <= 256)  Ps[1*2064 + wv*258 + jt]   = s1;
        if (jt >= 2 && jt <= 257)  Ps[2*2064 + wv*258 + jt-1] = s2;
      }
    }
  }
  __syncthreads();   // bar3

  // ---- softmax (per lane: oc = 64p+l) + in-place mix of own kk strips ----
  {
    float aw0[4], aw1[4], aw2[4];
    #pragma unroll
    for (int p = 0; p < 4; ++p) {
      int oc = 64*p + l;
      int jp = oc + 1;
      float d0 = 0.f, d1 = 0.f, d2 = 0.f;
      #pragma unroll
      for (int g = 0; g < 8; ++g) {
        d0 += Ps[0*2064 + g*258 + jp];
        d1 += Ps[1*2064 + g*258 + jp];
        d2 += Ps[2*2064 + g*258 + jp];
      }
      float am = ABs[jp-1], ac_ = ABs[jp], ap_ = ABs[jp+1];
      float be = ABs[258 + jp];
      float sc0 = (d0 + am + be + c0) * 0.0625f;
      float sc1 = (d1 + ac_ + be + c0) * 0.0625f;
      float sc2 = (d2 + ap_ + be + c0) * 0.0625f;
      int w = w0 + oc;
      bool v0 = (w >= 1), v2 = (w + 1 < W_DIM);
      const float NEG = -1e30f;
      float m = fmaxf(v0 ? sc0 : NEG, fmaxf(sc1, v2 ? sc2 : NEG));
      float e0v = v0 ? __expf(sc0 - m) : 0.f;
      float e1v = __expf(sc1 - m);
      float e2v = v2 ? __expf(sc2 - m) : 0.f;
      float inv = 1.f / (e0v + e1v + e2v);
      aw0[p] = e0v*inv; aw1[p] = e1v*inv; aw2[p] = e2v*inv;
    }
    // mix: out col oc uses x at j = oc, oc+1, oc+2; write at j' = oc+1.
    // All 12 reads issued before any write (in-order LDS within wave).
    #pragma unroll
    for (int g = 0; g < 4; ++g) {
      u16* base = Xt + (4*wv + g)*259*8;
      u16x8 xrd[12];
      #pragma unroll
      for (int p = 0; p < 4; ++p)
        #pragma unroll
        for (int i = 0; i < 3; ++i)
          xrd[p*3+i] = *reinterpret_cast<const u16x8*>(base + (64*p + l + i)*8);
      __builtin_amdgcn_sched_barrier(0);
      #pragma unroll
      for (int p = 0; p < 4; ++p) {
        union { u16 u[8]; u16x8 v; } pk;
        #pragma unroll
        for (int e = 0; e < 8; ++e)
          pk.u[e] = f2b(aw0[p]*b2f(xrd[p*3][e]) + aw1[p]*b2f(xrd[p*3+1][e])
                        + aw2[p]*b2f(xrd[p*3+2][e]));
        *reinterpret_cast<u16x8*>(base + (64*p + l + 1)*8) = pk.v;
      }
      __builtin_amdgcn_sched_barrier(0);
    }
  }
  __syncthreads();   // bar4

  // ---- GEMM2: out = Wv @ Xmix + bv, 8 n-tiles, dense aligned stores ----
  {
    f32x16 acc2[8];
    #pragma unroll
    for (int n = 0; n < 8; ++n)
      #pragma unroll
      for (int r = 0; r < 16; ++r) acc2[n][r] = 0.f;
    const u16* Arow2 = Wvb + (32*wv + col)*256 + 8*half;
    #pragma unroll
    for (int kk = 0; kk < 16; ++kk) {
      s16x8 a = *reinterpret_cast<const s16x8*>(Arow2 + 16*kk);
      const u16* Bb = Xt + (2*kk + half)*259*8;
      #pragma unroll
      for (int n = 0; n < 8; ++n) {
        s16x8 bfr = *reinterpret_cast<const s16x8*>(Bb + (1 + 32*n + col)*8);
        acc2[n] = __builtin_amdgcn_mfma_f32_32x32x16_bf16(a, bfr, acc2[n], 0, 0, 0);
      }
    }
    float bvr[16];
    #pragma unroll
    for (int q = 0; q < 4; ++q) {
      const float4 t4 = *reinterpret_cast<const float4*>(bvs + 32*wv + 8*q + 4*half);
      bvr[4*q+0] = t4.x; bvr[4*q+1] = t4.y; bvr[4*q+2] = t4.z; bvr[4*q+3] = t4.w;
    }
    #pragma unroll
    for (int n = 0; n < 8; ++n)
      #pragma unroll
      for (int r = 0; r < 16; ++r) {
        int crow = 32*wv + (r&3) + 8*(r>>2) + 4*half;
        outb[(size_t)crow*W_DIM + w0 + 32*n + col] = acc2[n][r] + bvr[r];
      }
  }
}

extern "C" void kernel_launch(void* const* d_in, const int* in_sizes, int n_in,
                              void* d_out, int out_size, void* d_ws, size_t ws_size,
                              hipStream_t stream) {
  (void)in_sizes; (void)n_in; (void)out_size; (void)ws_size;
  const float* x  = (const float*)d_in[0];
  const float* Wq = (const float*)d_in[1];
  const float* bq = (const float*)d_in[2];
  const float* Wk = (const float*)d_in[3];
  const float* bk = (const float*)d_in[4];
  const float* Wv = (const float*)d_in[5];
  const float* bv = (const float*)d_in[6];
  float* out = (float*)d_out;
  char* ws = (char*)d_ws;   // needs 264196 B

  hipFuncSetAttribute((const void*)main_kernel,
                      hipFuncAttributeMaxDynamicSharedMemorySize, LDS_BYTES);
  prep_kernel<<<321, 256, 0, stream>>>(Wq, bq, Wk, bk, Wv, ws);
  main_kernel<<<256, 512, LDS_BYTES, stream>>>(x, ws, bv, out);
}